// Round 6
// baseline (222.377 us; speedup 1.0000x reference)
//
#include <hip/hip_runtime.h>
#include <hip/hip_bf16.h>
#include <stdint.h>

#define NN 4096
#define KIN 512
#define HH 8
#define HF 256
#define LOG2E 1.4426950408889634f

typedef float f32x4 __attribute__((ext_vector_type(4)));
typedef short s16x8 __attribute__((ext_vector_type(8)));
typedef __bf16 bf16x8 __attribute__((ext_vector_type(8)));
typedef unsigned int u32x4 __attribute__((ext_vector_type(4)));

#if defined(__has_builtin)
#if __has_builtin(__builtin_amdgcn_exp2f)
#define EXP2(x) __builtin_amdgcn_exp2f(x)
#else
#define EXP2(x) exp2f(x)
#endif
#else
#define EXP2(x) exp2f(x)
#endif

// ---------------------------------------------------------------------------
// k_prep: x = node@W via bf16 MFMA (64x64 tiles). Emits XT (bf16 [256][4096],
// coalesced via LDS transpose), sSrcT/sTgtT ([8][4096], log2-domain), flag.
// ---------------------------------------------------------------------------
__global__ __launch_bounds__(256) void k_prep(
    const float* __restrict__ node, const float* __restrict__ Wm,
    const float* __restrict__ avec, const void* __restrict__ adjv,
    uint16_t* __restrict__ XT, float* __restrict__ sSrcT,
    float* __restrict__ sTgtT, int* __restrict__ flag) {
  if (blockIdx.x == 0 && blockIdx.y == 0 && threadIdx.x == 0) {
    const uint32_t* aw = (const uint32_t*)adjv;
    const uint32_t w0 = aw[0];
    int f;
    if (w0 == 0x3F800000u) f = 2;                 // fp32 0/1
    else if ((w0 & 0xFFFFu) == 0x3F80u) f = 3;    // bf16 0/1
    else {
      int alli = 1;
      for (int k = 0; k < 64; ++k)
        if (aw[k] > 1u) { alli = 0; break; }
      f = alli ? 1 : 0;                           // int32 : uint8
    }
    *flag = f;
  }

  __shared__ __bf16 Ald[64][40];
  __shared__ __bf16 Bld[64][40];
  __shared__ __bf16 Cs[64][72];
  const int tid = threadIdx.x;
  const int wv = tid >> 6, ln = tid & 63, nl = ln & 15, qd = ln >> 4;
  const int row0 = blockIdx.x * 64, col0 = blockIdx.y * 64;
  const int rA = tid >> 2, kA = (tid & 3) * 8;
  const int kB = tid >> 3, cB = (tid & 7) * 8;

  f32x4 acc[4] = {{0,0,0,0},{0,0,0,0},{0,0,0,0},{0,0,0,0}};
  float4 a0, a1, b0, b1;

  auto ldg = [&](int k0) {
    a0 = *(const float4*)(node + (size_t)(row0 + rA) * KIN + k0 + kA);
    a1 = *(const float4*)(node + (size_t)(row0 + rA) * KIN + k0 + kA + 4);
    b0 = *(const float4*)(Wm + (size_t)(k0 + kB) * HF + col0 + cB);
    b1 = *(const float4*)(Wm + (size_t)(k0 + kB) * HF + col0 + cB + 4);
  };

  ldg(0);
  for (int k0 = 0; k0 < KIN; k0 += 32) {
    __syncthreads();
    {
      union { bf16x8 v; s16x8 s; } pk;
      pk.v[0] = (__bf16)a0.x; pk.v[1] = (__bf16)a0.y;
      pk.v[2] = (__bf16)a0.z; pk.v[3] = (__bf16)a0.w;
      pk.v[4] = (__bf16)a1.x; pk.v[5] = (__bf16)a1.y;
      pk.v[6] = (__bf16)a1.z; pk.v[7] = (__bf16)a1.w;
      *(s16x8*)&Ald[rA][kA] = pk.s;
      Bld[cB + 0][kB] = (__bf16)b0.x;
      Bld[cB + 1][kB] = (__bf16)b0.y;
      Bld[cB + 2][kB] = (__bf16)b0.z;
      Bld[cB + 3][kB] = (__bf16)b0.w;
      Bld[cB + 4][kB] = (__bf16)b1.x;
      Bld[cB + 5][kB] = (__bf16)b1.y;
      Bld[cB + 6][kB] = (__bf16)b1.z;
      Bld[cB + 7][kB] = (__bf16)b1.w;
    }
    __syncthreads();
    if (k0 + 32 < KIN) ldg(k0 + 32);
    const s16x8 af = *(const s16x8*)&Ald[wv * 16 + nl][qd * 8];
#pragma unroll
    for (int ct = 0; ct < 4; ++ct) {
      const s16x8 bfr = *(const s16x8*)&Bld[ct * 16 + nl][qd * 8];
      acc[ct] = __builtin_amdgcn_mfma_f32_16x16x32_bf16(af, bfr, acc[ct], 0, 0, 0);
    }
  }

#pragma unroll
  for (int ct = 0; ct < 4; ++ct)
#pragma unroll
    for (int r = 0; r < 4; ++r)
      Cs[ct * 16 + nl][wv * 16 + qd * 4 + r] = (__bf16)acc[ct][r];
  __syncthreads();
  {
    const int xr = tid >> 2;
#pragma unroll
    for (int sseg = 0; sseg < 2; ++sseg) {
      const int sc = ((tid & 3) * 2 + sseg) * 8;
      *(s16x8*)(XT + (size_t)(col0 + xr) * NN + row0 + sc) =
          *(const s16x8*)&Cs[xr][sc];
    }
  }

  const float as0 = avec[nl] * LOG2E, as1 = avec[16 + nl] * LOG2E;
  const float at0 = avec[32 + nl] * LOG2E, at1 = avec[48 + nl] * LOG2E;
#pragma unroll
  for (int hp = 0; hp < 2; ++hp) {
    float ps[4], pt[4];
#pragma unroll
    for (int r = 0; r < 4; ++r) {
      ps[r] = acc[2 * hp][r] * as0 + acc[2 * hp + 1][r] * as1;
      pt[r] = acc[2 * hp][r] * at0 + acc[2 * hp + 1][r] * at1;
    }
#pragma unroll
    for (int m = 1; m <= 8; m <<= 1)
#pragma unroll
      for (int r = 0; r < 4; ++r) {
        ps[r] += __shfl_xor(ps[r], m);
        pt[r] += __shfl_xor(pt[r], m);
      }
    if (nl == 0) {
      const int h = blockIdx.y * 2 + hp;
#pragma unroll
      for (int r = 0; r < 4; ++r) {
        sSrcT[h * NN + row0 + wv * 16 + qd * 4 + r] = ps[r];
        sTgtT[h * NN + row0 + wv * 16 + qd * 4 + r] = pt[r];
      }
    }
  }
}

// ---------------------------------------------------------------------------
// k_attn: block = 64 target rows x 8 heads (8 waves, M=64 per wave).
// Adjacency: raw nontemporal loads issued BEFORE compute, decoded AFTER
// compute into a double-buffered LDS mask (one barrier per chunk) so the
// vmcnt wait never sits on the critical path. Mask applied as bitwise AND
// on packed bf16 P; den via ones-MFMA.
// ---------------------------------------------------------------------------
__global__ __launch_bounds__(512, 4) void k_attn(
    const void* __restrict__ adjv, const int* __restrict__ flagp,
    const uint16_t* __restrict__ XT, const float* __restrict__ sSrcT,
    const float* __restrict__ sTgtT, uint16_t* __restrict__ pnum,
    float* __restrict__ pden, float* __restrict__ out) {
  __shared__ uint16_t Msk[2][64][264];  // dbuf; stride 132 words: 2-way free
  const int tid = threadIdx.x;
  const int h = tid >> 6;
  const int ln = tid & 63, nl = ln & 15, qd = ln >> 4;
  const int tile = blockIdx.x, js = blockIdx.y, JS = gridDim.y;
  const int i0 = tile * 64;
  const int jlen = NN / JS, j0 = js * jlen, NC = jlen / 256;
  const int mode = *flagp;
  const int srow = tid >> 3, scb = (tid & 7) * 32;  // staging: row, col-base

  float tl[4];
#pragma unroll
  for (int ib = 0; ib < 4; ++ib)
    tl[ib] = sTgtT[h * NN + i0 + ib * 16 + nl];
  const float* sS = sSrcT + h * NN;
  const uint16_t* x0 = XT + (size_t)(h * 32 + nl) * NN;
  const uint16_t* x1 = x0 + (size_t)16 * NN;

  const short one_bf = (short)0x3F80;
  const s16x8 ONES = {one_bf, one_bf, one_bf, one_bf,
                      one_bf, one_bf, one_bf, one_bf};

  f32x4 acc0[4] = {{0,0,0,0},{0,0,0,0},{0,0,0,0},{0,0,0,0}};
  f32x4 acc1[4] = {{0,0,0,0},{0,0,0,0},{0,0,0,0},{0,0,0,0}};
  f32x4 accD[4] = {{0,0,0,0},{0,0,0,0},{0,0,0,0},{0,0,0,0}};

  u32x4 raw[8];  // raw adjacency words; decode deferred past compute

  auto loadRaw = [&](int jbase) {
    const size_t eidx = (size_t)(i0 + srow) * NN + jbase + scb;
    if (mode == 0) {            // 1 B/elem: 32 B
      const u32x4* p = (const u32x4*)((const uint8_t*)adjv + eidx);
#pragma unroll
      for (int k = 0; k < 2; ++k) raw[k] = __builtin_nontemporal_load(&p[k]);
    } else if (mode == 3) {     // 2 B/elem: 64 B
      const u32x4* p = (const u32x4*)((const uint16_t*)adjv + eidx);
#pragma unroll
      for (int k = 0; k < 4; ++k) raw[k] = __builtin_nontemporal_load(&p[k]);
    } else {                    // 4 B/elem: 128 B
      const u32x4* p = (const u32x4*)((const uint32_t*)adjv + eidx);
#pragma unroll
      for (int k = 0; k < 8; ++k) raw[k] = __builtin_nontemporal_load(&p[k]);
    }
  };

  auto decodeStore = [&](int buf) {
    union { uint16_t u[32]; s16x8 v[4]; } pre;
    if (mode == 0) {
#pragma unroll
      for (int k = 0; k < 2; ++k)
#pragma unroll
        for (int q = 0; q < 4; ++q)
#pragma unroll
          for (int b = 0; b < 4; ++b)
            pre.u[k * 16 + q * 4 + b] =
                ((raw[k][q] >> (8 * b)) & 0xFFu) ? 0xFFFFu : 0u;
    } else if (mode == 3) {
#pragma unroll
      for (int k = 0; k < 4; ++k)
#pragma unroll
        for (int q = 0; q < 4; ++q) {
          pre.u[k * 8 + q * 2 + 0] = (raw[k][q] & 0xFFFFu) ? 0xFFFFu : 0u;
          pre.u[k * 8 + q * 2 + 1] = (raw[k][q] >> 16) ? 0xFFFFu : 0u;
        }
    } else {
#pragma unroll
      for (int k = 0; k < 8; ++k)
#pragma unroll
        for (int q = 0; q < 4; ++q)
          pre.u[k * 4 + q] = raw[k][q] ? 0xFFFFu : 0u;
    }
#pragma unroll
    for (int seg = 0; seg < 4; ++seg)
      *(s16x8*)&Msk[buf][srow][scb + seg * 8] = pre.v[seg];
  };

  // prologue: chunk 0 decoded in place (only exposed latency of the kernel)
  loadRaw(j0);
  decodeStore(0);
  __syncthreads();

  s16x8 nbx0 = *(const s16x8*)(x0 + j0 + qd * 8);
  s16x8 nbx1 = *(const s16x8*)(x1 + j0 + qd * 8);

  for (int c = 0; c < NC; ++c) {
    const int cur = c & 1;
    const int jb = j0 + c * 256;
    if (c + 1 < NC) loadRaw(jb + 256);  // issue only; no consumer yet

#pragma unroll
    for (int st = 0; st < 8; ++st) {
      const s16x8 bx0 = nbx0, bx1 = nbx1;
      const int jq = st * 32 + qd * 8;
      // rolling prefetch, crossing the chunk boundary
      const int nj = (st < 7) ? (jb + jq + 32)
                              : ((c + 1 < NC) ? (jb + 256 + qd * 8) : (j0 + qd * 8));
      nbx0 = *(const s16x8*)(x0 + nj);
      nbx1 = *(const s16x8*)(x1 + nj);

      const f32x4 s0 = *(const f32x4*)(sS + jb + jq);
      const f32x4 s1 = *(const f32x4*)(sS + jb + jq + 4);
      const float sv[8] = {s0[0], s0[1], s0[2], s0[3],
                           s1[0], s1[1], s1[2], s1[3]};
#pragma unroll
      for (int ib = 0; ib < 4; ++ib) {
        const s16x8 mk = *(const s16x8*)&Msk[cur][ib * 16 + nl][jq];
        union { bf16x8 b; s16x8 s; } af;
#pragma unroll
        for (int cc = 0; cc < 8; ++cc) {
          const float v = tl[ib] + sv[cc];
          const float w = fmaxf(v, 0.2f * v);
          af.b[cc] = (__bf16)EXP2(w);
        }
        af.s = af.s & mk;
        acc0[ib] = __builtin_amdgcn_mfma_f32_16x16x32_bf16(af.s, bx0, acc0[ib], 0, 0, 0);
        acc1[ib] = __builtin_amdgcn_mfma_f32_16x16x32_bf16(af.s, bx1, acc1[ib], 0, 0, 0);
        accD[ib] = __builtin_amdgcn_mfma_f32_16x16x32_bf16(af.s, ONES, accD[ib], 0, 0, 0);
      }
    }

    if (c + 1 < NC) decodeStore(1 - cur);  // vmcnt wait lands here, post-compute
    __syncthreads();
  }

  if (JS == 1) {
#pragma unroll
    for (int ib = 0; ib < 4; ++ib)
#pragma unroll
      for (int r = 0; r < 4; ++r) {
        const int rw = ib * 16 + qd * 4 + r;
        const float inv = 1.0f / accD[ib][r];
        out[(size_t)(i0 + rw) * HF + h * 32 + nl] = acc0[ib][r] * inv;
        out[(size_t)(i0 + rw) * HF + h * 32 + 16 + nl] = acc1[ib][r] * inv;
      }
  } else {
    union { __bf16 b; uint16_t u; } cv;
#pragma unroll
    for (int ib = 0; ib < 4; ++ib) {
      const int t16 = tile * 4 + ib;
      const size_t pb = (((size_t)js * 256 + t16) * HH + h) * 2;
#pragma unroll
      for (int r = 0; r < 4; ++r) {
        const int rw = qd * 4 + r;
        cv.b = (__bf16)acc0[ib][r];
        pnum[(pb * 16 + rw) * 16 + nl] = cv.u;
        cv.b = (__bf16)acc1[ib][r];
        pnum[((pb + 1) * 16 + rw) * 16 + nl] = cv.u;
      }
      if (nl == 0) {
#pragma unroll
        for (int r = 0; r < 4; ++r)
          pden[((size_t)js * 256 + t16) * 128 + h * 16 + qd * 4 + r] =
              accD[ib][r];
      }
    }
  }
}

// ---------------------------------------------------------------------------
__global__ __launch_bounds__(256) void k_reduce(
    const uint16_t* __restrict__ pnum, const float* __restrict__ pden,
    float* __restrict__ out, int JS) {
  const int gid = blockIdx.x * 256 + threadIdx.x;
  const int i = gid >> 8, col = gid & 255;
  const int tile = i >> 4, r = i & 15;
  const int h = col >> 5, ct = (col >> 4) & 1, cc = col & 15;
  float num = 0.f, den = 0.f;
  for (int js = 0; js < JS; ++js) {
    union { uint16_t u; __bf16 b; } cv;
    cv.u = pnum[(((((size_t)js * 256 + tile) * 8 + h) * 2 + ct) * 16 + r) * 16 + cc];
    num += (float)cv.b;
    den += pden[((size_t)js * 256 + tile) * 128 + h * 16 + r];
  }
  out[gid] = num / den;
}

// ---------------------------------------------------------------------------
extern "C" void kernel_launch(void* const* d_in, const int* in_sizes, int n_in,
                              void* d_out, int out_size, void* d_ws, size_t ws_size,
                              hipStream_t stream) {
  const float* node = (const float*)d_in[0];
  const void* adj = d_in[1];
  const float* Wm = (const float*)d_in[2];
  const float* avec = (const float*)d_in[3];
  float* out = (float*)d_out;

  uint8_t* ws = (uint8_t*)d_ws;
  uint16_t* XT = (uint16_t*)ws;                        // 2 MB
  float* sSrcT = (float*)(ws + 0x200000);              // 128 KB
  float* sTgtT = (float*)(ws + 0x220000);              // 128 KB
  int* flag = (int*)(ws + 0x240000);                   // 4 B (pad 1 KB)
  const size_t base = 0x240400;
  const size_t per = 2097152ull + 131072ull;           // pnum + pden per slice
  int JS = 1;
  if (ws_size >= base + 8 * per) JS = 8;
  else if (ws_size >= base + 4 * per) JS = 4;
  else if (ws_size >= base + 2 * per) JS = 2;
  uint16_t* pnum = (uint16_t*)(ws + base);
  float* pden = (float*)(ws + base + (size_t)JS * 2097152ull);

  hipLaunchKernelGGL(k_prep, dim3(64, 4), dim3(256), 0, stream,
                     node, Wm, avec, adj, XT, sSrcT, sTgtT, flag);
  hipLaunchKernelGGL(k_attn, dim3(64, JS), dim3(512), 0, stream,
                     adj, flag, XT, sSrcT, sTgtT, pnum, pden, out);
  if (JS > 1)
    hipLaunchKernelGGL(k_reduce, dim3(4096), dim3(256), 0, stream,
                       pnum, pden, out, JS);
}